// Round 1
// baseline (5427.218 us; speedup 1.0000x reference)
//
#include <hip/hip_runtime.h>

// GLM block input transform: h = xs@W_aff.T + b_aff; qkv = h@W_qkv.T + b_qkv;
// split into q,k,v per head; RoPE(q,k) with 2 position streams; out = [q|k|v] fp32.
// S=2048 B=4 D=4096 H=32 HD=128 RD=64.
//
// Strategy: fp32 -> (hi,lo) bf16 split; C = Ah*Bh + Ah*Bl + Al*Bh via
// mfma_f32_16x16x32_bf16 (fp32-quality, ~3.3 TFLOP-equiv at bf16 MFMA rate).
// GEMM: 128x128 tile, BK=32, 4 waves (2x2), 4x4 frags/wave, global_load_lds
// staging (width=16), single-buffered LDS. RoPE+bias fused into GEMM2 epilogue.

typedef __bf16 bf16;
typedef __bf16 bf16x8 __attribute__((ext_vector_type(8)));
typedef __bf16 bf16x4 __attribute__((ext_vector_type(4)));
typedef float f32x4 __attribute__((ext_vector_type(4)));

#define GLD16(gp, lp) __builtin_amdgcn_global_load_lds(                     \
    (const __attribute__((address_space(1))) void*)(gp),                    \
    (__attribute__((address_space(3))) void*)(lp), 16, 0, 0)

constexpr int Ssz = 2048;
constexpr int Kd  = 4096;             // K of both GEMMs
constexpr long OUTP = 33554432;       // S*B*D elements per output tensor

// ---------------- fp32 -> hi/lo bf16 split ----------------
__global__ void split_kernel(const float* __restrict__ x, bf16* __restrict__ hi,
                             bf16* __restrict__ lo, int n4) {
  int idx = blockIdx.x * blockDim.x + threadIdx.x;
  int stride = gridDim.x * blockDim.x;
  const float4* xv = (const float4*)x;
  bf16x4* hv = (bf16x4*)hi;
  bf16x4* lv = (bf16x4*)lo;
  for (int i = idx; i < n4; i += stride) {
    float4 v = xv[i];
    bf16x4 h, l;
    h[0] = (bf16)v.x; l[0] = (bf16)(v.x - (float)h[0]);
    h[1] = (bf16)v.y; l[1] = (bf16)(v.y - (float)h[1]);
    h[2] = (bf16)v.z; l[2] = (bf16)(v.z - (float)h[2]);
    h[3] = (bf16)v.w; l[3] = (bf16)(v.w - (float)h[3]);
    hv[i] = h; lv[i] = l;
  }
}

// ---------------- RoPE cos/sin table [2048][32] ----------------
__global__ void rope_table_kernel(const float* __restrict__ invf,
                                  float* __restrict__ cost, float* __restrict__ sint) {
  int idx = blockIdx.x * blockDim.x + threadIdx.x;  // 65536 = 2048*32
  int p = idx >> 5, i = idx & 31;
  float a = (float)p * invf[i];
  cost[idx] = cosf(a);
  sint[idx] = sinf(a);
}

// ---------------- split-bf16 GEMM, C = A @ B^T (+bias, +epilogue) ----------
// A: [M][4096] as hi/lo bf16; B: [N][4096] as hi/lo bf16 (row = output feature).
// EPI=0: write h as hi/lo bf16 [M][4096] (bias added).
// EPI=1: qkv epilogue: bias + RoPE for q/k parts, scatter to out fp32.
template <int EPI>
__global__ __launch_bounds__(256, 2)
void gemm_split_kernel(const bf16* __restrict__ Ahi, const bf16* __restrict__ Alo,
                       const bf16* __restrict__ Bhi, const bf16* __restrict__ Blo,
                       const float* __restrict__ bias,
                       bf16* __restrict__ Chi, bf16* __restrict__ Clo,
                       float* __restrict__ out, const int* __restrict__ pid,
                       const float* __restrict__ cost, const float* __restrict__ sint) {
  __shared__ __align__(16) bf16 smem[16384];  // 32 KiB: 4 x [128][32]
  bf16* As_hi = smem;
  bf16* As_lo = smem + 4096;
  bf16* Bs_hi = smem + 8192;
  bf16* Bs_lo = smem + 12288;

  const int t = threadIdx.x;
  const int lane = t & 63;
  const int w = t >> 6;               // wave 0..3
  const int wr = w >> 1, wc = w & 1;  // wave grid 2x2 (64x64 per wave)
  const int tn = blockIdx.x, tm = blockIdx.y;

  // staging: thread t of issue j covers LDS 16B-slot (j*256+t);
  // row = j*64 + (t>>2), col = (t&3)*8  -> linear row-major [128][32].
  const int srow = t >> 2;
  const int scol = (t & 3) * 8;
  const bf16* gAh = Ahi + (long)(tm * 128 + srow) * Kd + scol;
  const bf16* gAl = Alo + (long)(tm * 128 + srow) * Kd + scol;
  const bf16* gBh = Bhi + (long)(tn * 128 + srow) * Kd + scol;
  const bf16* gBl = Blo + (long)(tn * 128 + srow) * Kd + scol;
  const int ldsb = w * 512;  // wave-uniform LDS element base (+2048 for j=1)

  const int kc = (lane >> 4) * 8;  // k-chunk of this lane's fragment
  const int la = lane & 15;        // row/col within fragment

  f32x4 acc[4][4];
#pragma unroll
  for (int m = 0; m < 4; ++m)
#pragma unroll
    for (int n = 0; n < 4; ++n) acc[m][n] = (f32x4){0.f, 0.f, 0.f, 0.f};

  for (int k0 = 0; k0 < Kd; k0 += 32) {
    GLD16(gAh + k0, As_hi + ldsb);
    GLD16(gAh + 64 * Kd + k0, As_hi + 2048 + ldsb);
    GLD16(gAl + k0, As_lo + ldsb);
    GLD16(gAl + 64 * Kd + k0, As_lo + 2048 + ldsb);
    GLD16(gBh + k0, Bs_hi + ldsb);
    GLD16(gBh + 64 * Kd + k0, Bs_hi + 2048 + ldsb);
    GLD16(gBl + k0, Bs_lo + ldsb);
    GLD16(gBl + 64 * Kd + k0, Bs_lo + 2048 + ldsb);
    __syncthreads();  // drains vmcnt -> tiles visible to all waves

    bf16x8 ah[4], al[4], bh[4], bl[4];
#pragma unroll
    for (int m = 0; m < 4; ++m) {
      int off = (wr * 64 + m * 16 + la) * 32 + kc;
      ah[m] = *(const bf16x8*)(As_hi + off);
      al[m] = *(const bf16x8*)(As_lo + off);
    }
#pragma unroll
    for (int n = 0; n < 4; ++n) {
      int off = (wc * 64 + n * 16 + la) * 32 + kc;
      bh[n] = *(const bf16x8*)(Bs_hi + off);
      bl[n] = *(const bf16x8*)(Bs_lo + off);
    }
#pragma unroll
    for (int m = 0; m < 4; ++m)
#pragma unroll
      for (int n = 0; n < 4; ++n) {
        acc[m][n] = __builtin_amdgcn_mfma_f32_16x16x32_bf16(ah[m], bh[n], acc[m][n], 0, 0, 0);
        acc[m][n] = __builtin_amdgcn_mfma_f32_16x16x32_bf16(ah[m], bl[n], acc[m][n], 0, 0, 0);
        acc[m][n] = __builtin_amdgcn_mfma_f32_16x16x32_bf16(al[m], bh[n], acc[m][n], 0, 0, 0);
      }
    __syncthreads();  // protect LDS from next iteration's staging
  }

  // ---- epilogue ----  C/D frag: col = lane&15, row = (lane>>4)*4 + reg
  const long crow0 = (long)tm * 128 + wr * 64;
  if (EPI == 0) {
    const int ccol0 = tn * 128 + wc * 64;
#pragma unroll
    for (int n = 0; n < 4; ++n) {
      int col = ccol0 + n * 16 + la;
      float bv = bias[col];
#pragma unroll
      for (int m = 0; m < 4; ++m)
#pragma unroll
        for (int r = 0; r < 4; ++r) {
          long row = crow0 + m * 16 + (lane >> 4) * 4 + r;
          float v = acc[m][n][r] + bv;
          bf16 h = (bf16)v;
          bf16 l = (bf16)(v - (float)h);
          Chi[row * 4096 + col] = h;
          Clo[row * 4096 + col] = l;
        }
    }
  } else {
    // column tile tn covers cols [tn*128, tn*128+128): head = tn/3, part = tn%3
    const int head = tn / 3, part = tn % 3;
    const long obase = (long)part * OUTP + (long)head * 128;
    if (part == 2) {  // v: bias only
#pragma unroll
      for (int n = 0; n < 4; ++n) {
        int hd = wc * 64 + n * 16 + la;
        float bv = bias[tn * 128 + hd];
#pragma unroll
        for (int m = 0; m < 4; ++m)
#pragma unroll
          for (int r = 0; r < 4; ++r) {
            long rr = crow0 + m * 16 + (lane >> 4) * 4 + r;
            out[obase + rr * 4096 + hd] = acc[m][n][r] + bv;
          }
      }
    } else {  // q/k: RoPE. wave col-half wc = rotary half (0: pos, 1: bpos)
      const int half = wc;
      float bv1[2], bv2[2];
#pragma unroll
      for (int n = 0; n < 2; ++n) {
        bv1[n] = bias[tn * 128 + half * 64 + n * 16 + la];
        bv2[n] = bias[tn * 128 + half * 64 + n * 16 + la + 32];
      }
#pragma unroll
      for (int m = 0; m < 4; ++m)
#pragma unroll
        for (int r = 0; r < 4; ++r) {
          long rr = crow0 + m * 16 + (lane >> 4) * 4 + r;  // rr = s*4 + b
          int s = (int)(rr >> 2), b = (int)(rr & 3);
          int p0 = pid[b * 2 * Ssz + half * Ssz + s];
#pragma unroll
          for (int n = 0; n < 2; ++n) {
            int i = n * 16 + la;  // 0..31 within the 64-wide half
            float c = cost[p0 * 32 + i];
            float sn = sint[p0 * 32 + i];
            float x1 = acc[m][n][r] + bv1[n];      // x[i]
            float x2 = acc[m][n + 2][r] + bv2[n];  // x[i+32]
            long o = obase + rr * 4096 + half * 64 + i;
            out[o] = x1 * c - x2 * sn;
            out[o + 32] = x2 * c + x1 * sn;
          }
        }
    }
  }
}

// ---------------- launch ----------------
extern "C" void kernel_launch(void* const* d_in, const int* in_sizes, int n_in,
                              void* d_out, int out_size, void* d_ws, size_t ws_size,
                              hipStream_t stream) {
  const float* xs   = (const float*)d_in[0];
  const int*   pid  = (const int*)d_in[1];
  const float* Waff = (const float*)d_in[2];
  const float* baff = (const float*)d_in[3];
  const float* Wqkv = (const float*)d_in[4];
  const float* bqkv = (const float*)d_in[5];
  const float* invf = (const float*)d_in[6];
  float* out = (float*)d_out;

  // workspace layout (~538 MB total)
  char* p = (char*)d_ws;
  bf16* A_hi  = (bf16*)p; p += (long)33554432 * 2;
  bf16* A_lo  = (bf16*)p; p += (long)33554432 * 2;
  bf16* Wa_hi = (bf16*)p; p += (long)16777216 * 2;
  bf16* Wa_lo = (bf16*)p; p += (long)16777216 * 2;
  bf16* Wq_hi = (bf16*)p; p += (long)50331648 * 2;
  bf16* Wq_lo = (bf16*)p; p += (long)50331648 * 2;
  bf16* h_hi  = (bf16*)p; p += (long)33554432 * 2;
  bf16* h_lo  = (bf16*)p; p += (long)33554432 * 2;
  float* cost = (float*)p; p += 65536 * 4;
  float* sint = (float*)p; p += 65536 * 4;

  split_kernel<<<2048, 256, 0, stream>>>(xs, A_hi, A_lo, 33554432 / 4);
  split_kernel<<<2048, 256, 0, stream>>>(Waff, Wa_hi, Wa_lo, 16777216 / 4);
  split_kernel<<<2048, 256, 0, stream>>>(Wqkv, Wq_hi, Wq_lo, 50331648 / 4);
  rope_table_kernel<<<256, 256, 0, stream>>>(invf, cost, sint);

  dim3 g1(4096 / 128, 8192 / 128);  // (ntn, ntm)
  gemm_split_kernel<0><<<g1, 256, 0, stream>>>(A_hi, A_lo, Wa_hi, Wa_lo, baff,
                                               h_hi, h_lo, nullptr, nullptr,
                                               nullptr, nullptr);
  dim3 g2(12288 / 128, 8192 / 128);
  gemm_split_kernel<1><<<g2, 256, 0, stream>>>(h_hi, h_lo, Wq_hi, Wq_lo, bqkv,
                                               nullptr, nullptr, out, pid, cost,
                                               sint);
}

// Round 9
// 5247.621 us; speedup vs baseline: 1.0342x; 1.0342x over previous
//
#include <hip/hip_runtime.h>

// GLM block input transform: h = xs@W_aff.T + b_aff; qkv = h@W_qkv.T + b_qkv;
// split into q,k,v per head; RoPE(q,k) with 2 position streams; out = [q|k|v] fp32.
// S=2048 B=4 D=4096 H=32 HD=128 RD=64.
//
// Strategy: fp32 -> (hi,lo) bf16 split; C = Ah*Bh + Ah*Bl + Al*Bh via
// mfma_f32_16x16x32_bf16 (fp32-quality). 128x128 tile, BK=32, 4 waves (2x2),
// global_load_lds staging. R1: band-major block remap (L2/L3 locality) +
// slot-XOR LDS swizzle (bank-conflict-free b128 fragment reads).

typedef __bf16 bf16;
typedef __bf16 bf16x8 __attribute__((ext_vector_type(8)));
typedef __bf16 bf16x4 __attribute__((ext_vector_type(4)));
typedef float f32x4 __attribute__((ext_vector_type(4)));

#define GLD16(gp, lp) __builtin_amdgcn_global_load_lds(                     \
    (const __attribute__((address_space(1))) void*)(gp),                    \
    (__attribute__((address_space(3))) void*)(lp), 16, 0, 0)

constexpr int Ssz = 2048;
constexpr int Kd  = 4096;             // K of both GEMMs
constexpr long OUTP = 33554432;       // S*B*D elements per output tensor

// ---------------- fp32 -> hi/lo bf16 split ----------------
__global__ void split_kernel(const float* __restrict__ x, bf16* __restrict__ hi,
                             bf16* __restrict__ lo, int n4) {
  int idx = blockIdx.x * blockDim.x + threadIdx.x;
  int stride = gridDim.x * blockDim.x;
  const float4* xv = (const float4*)x;
  bf16x4* hv = (bf16x4*)hi;
  bf16x4* lv = (bf16x4*)lo;
  for (int i = idx; i < n4; i += stride) {
    float4 v = xv[i];
    bf16x4 h, l;
    h[0] = (bf16)v.x; l[0] = (bf16)(v.x - (float)h[0]);
    h[1] = (bf16)v.y; l[1] = (bf16)(v.y - (float)h[1]);
    h[2] = (bf16)v.z; l[2] = (bf16)(v.z - (float)h[2]);
    h[3] = (bf16)v.w; l[3] = (bf16)(v.w - (float)h[3]);
    hv[i] = h; lv[i] = l;
  }
}

// ---------------- RoPE cos/sin table [2048][32] ----------------
__global__ void rope_table_kernel(const float* __restrict__ invf,
                                  float* __restrict__ cost, float* __restrict__ sint) {
  int idx = blockIdx.x * blockDim.x + threadIdx.x;  // 65536 = 2048*32
  int p = idx >> 5, i = idx & 31;
  float a = (float)p * invf[i];
  cost[idx] = cosf(a);
  sint[idx] = sinf(a);
}

// ---------------- split-bf16 GEMM, C = A @ B^T (+bias, +epilogue) ----------
// 1D grid, band-major: 512 blocks/band = 64 row-tiles x 8 col-tiles, col
// fastest (8 = #XCDs; round-robin dispatch pins one B col-strip per XCD L2).
// LDS swizzle: 16B slot s holds global k-slot (s&3)^((s>>3)&3) of row s>>2
// (involution; global_load_lds dest stays linear, source is pre-swizzled).
template <int EPI>
__global__ __launch_bounds__(256, 4)
void gemm_split_kernel(const bf16* __restrict__ Ahi, const bf16* __restrict__ Alo,
                       const bf16* __restrict__ Bhi, const bf16* __restrict__ Blo,
                       const float* __restrict__ bias,
                       bf16* __restrict__ Chi, bf16* __restrict__ Clo,
                       float* __restrict__ out, const int* __restrict__ pid,
                       const float* __restrict__ cost, const float* __restrict__ sint) {
  __shared__ __align__(16) bf16 smem[16384];  // 32 KiB: 4 x [128][32]
  bf16* As_hi = smem;
  bf16* As_lo = smem + 4096;
  bf16* Bs_hi = smem + 8192;
  bf16* Bs_lo = smem + 12288;

  const int t = threadIdx.x;
  const int lane = t & 63;
  const int w = t >> 6;               // wave 0..3
  const int wr = w >> 1, wc = w & 1;  // wave grid 2x2 (64x64 per wave)

  const int bid = blockIdx.x;
  const int tn = (bid >> 9) * 8 + (bid & 7);  // band*8 + col
  const int tm = (bid & 511) >> 3;            // row-tile 0..63

  // staging: thread t -> LDS 16B-slot t (j=0) / 256+t (j=1), linear dest.
  // global source col pre-swizzled: gslot = (t&3) ^ ((t>>3)&3).
  const int srow = t >> 2;
  const int scol = ((t & 3) ^ ((t >> 3) & 3)) * 8;
  const bf16* gAh = Ahi + (long)(tm * 128 + srow) * Kd + scol;
  const bf16* gAl = Alo + (long)(tm * 128 + srow) * Kd + scol;
  const bf16* gBh = Bhi + (long)(tn * 128 + srow) * Kd + scol;
  const bf16* gBl = Blo + (long)(tn * 128 + srow) * Kd + scol;
  const int ldsb = w * 512;  // wave-uniform LDS element base (+2048 for j=1)

  const int la = lane & 15;  // row/col within fragment
  // swizzled k-offset: kslot ^ ((row>>1)&3) ; (row>>1)&3 == (la>>1)&3 for all m/wr
  const int kxor = ((lane >> 4) ^ ((la >> 1) & 3)) * 8;

  f32x4 acc[4][4];
#pragma unroll
  for (int m = 0; m < 4; ++m)
#pragma unroll
    for (int n = 0; n < 4; ++n) acc[m][n] = (f32x4){0.f, 0.f, 0.f, 0.f};

  for (int k0 = 0; k0 < Kd; k0 += 32) {
    GLD16(gAh + k0, As_hi + ldsb);
    GLD16(gAh + 64 * Kd + k0, As_hi + 2048 + ldsb);
    GLD16(gAl + k0, As_lo + ldsb);
    GLD16(gAl + 64 * Kd + k0, As_lo + 2048 + ldsb);
    GLD16(gBh + k0, Bs_hi + ldsb);
    GLD16(gBh + 64 * Kd + k0, Bs_hi + 2048 + ldsb);
    GLD16(gBl + k0, Bs_lo + ldsb);
    GLD16(gBl + 64 * Kd + k0, Bs_lo + 2048 + ldsb);
    __syncthreads();  // drains vmcnt -> tiles visible to all waves

    bf16x8 ah[4], al[4], bh[4], bl[4];
#pragma unroll
    for (int m = 0; m < 4; ++m) {
      int off = (wr * 64 + m * 16 + la) * 32 + kxor;
      ah[m] = *(const bf16x8*)(As_hi + off);
      al[m] = *(const bf16x8*)(As_lo + off);
    }
#pragma unroll
    for (int n = 0; n < 4; ++n) {
      int off = (wc * 64 + n * 16 + la) * 32 + kxor;
      bh[n] = *(const bf16x8*)(Bs_hi + off);
      bl[n] = *(const bf16x8*)(Bs_lo + off);
    }
#pragma unroll
    for (int m = 0; m < 4; ++m)
#pragma unroll
      for (int n = 0; n < 4; ++n) {
        acc[m][n] = __builtin_amdgcn_mfma_f32_16x16x32_bf16(ah[m], bh[n], acc[m][n], 0, 0, 0);
        acc[m][n] = __builtin_amdgcn_mfma_f32_16x16x32_bf16(ah[m], bl[n], acc[m][n], 0, 0, 0);
        acc[m][n] = __builtin_amdgcn_mfma_f32_16x16x32_bf16(al[m], bh[n], acc[m][n], 0, 0, 0);
      }
    __syncthreads();  // protect LDS from next iteration's staging
  }

  // ---- epilogue ----  C/D frag: col = lane&15, row = (lane>>4)*4 + reg
  const long crow0 = (long)tm * 128 + wr * 64;
  if (EPI == 0) {
    const int ccol0 = tn * 128 + wc * 64;
#pragma unroll
    for (int n = 0; n < 4; ++n) {
      int col = ccol0 + n * 16 + la;
      float bv = bias[col];
#pragma unroll
      for (int m = 0; m < 4; ++m)
#pragma unroll
        for (int r = 0; r < 4; ++r) {
          long row = crow0 + m * 16 + (lane >> 4) * 4 + r;
          float v = acc[m][n][r] + bv;
          bf16 h = (bf16)v;
          bf16 l = (bf16)(v - (float)h);
          Chi[row * 4096 + col] = h;
          Clo[row * 4096 + col] = l;
        }
    }
  } else {
    // column tile tn covers cols [tn*128, tn*128+128): head = tn/3, part = tn%3
    const int head = tn / 3, part = tn % 3;
    const long obase = (long)part * OUTP + (long)head * 128;
    if (part == 2) {  // v: bias only
#pragma unroll
      for (int n = 0; n < 4; ++n) {
        int hd = wc * 64 + n * 16 + la;
        float bv = bias[tn * 128 + hd];
#pragma unroll
        for (int m = 0; m < 4; ++m)
#pragma unroll
          for (int r = 0; r < 4; ++r) {
            long rr = crow0 + m * 16 + (lane >> 4) * 4 + r;
            out[obase + rr * 4096 + hd] = acc[m][n][r] + bv;
          }
      }
    } else {  // q/k: RoPE. wave col-half wc = rotary half (0: pos, 1: bpos)
      const int half = wc;
      float bv1[2], bv2[2];
#pragma unroll
      for (int n = 0; n < 2; ++n) {
        bv1[n] = bias[tn * 128 + half * 64 + n * 16 + la];
        bv2[n] = bias[tn * 128 + half * 64 + n * 16 + la + 32];
      }
#pragma unroll
      for (int m = 0; m < 4; ++m)
#pragma unroll
        for (int r = 0; r < 4; ++r) {
          long rr = crow0 + m * 16 + (lane >> 4) * 4 + r;  // rr = s*4 + b
          int s = (int)(rr >> 2), b = (int)(rr & 3);
          int p0 = pid[b * 2 * Ssz + half * Ssz + s];
#pragma unroll
          for (int n = 0; n < 2; ++n) {
            int i = n * 16 + la;  // 0..31 within the 64-wide half
            float c = cost[p0 * 32 + i];
            float sn = sint[p0 * 32 + i];
            float x1 = acc[m][n][r] + bv1[n];      // x[i]
            float x2 = acc[m][n + 2][r] + bv2[n];  // x[i+32]
            long o = obase + rr * 4096 + half * 64 + i;
            out[o] = x1 * c - x2 * sn;
            out[o + 32] = x2 * c + x1 * sn;
          }
        }
    }
  }
}

// ---------------- launch ----------------
extern "C" void kernel_launch(void* const* d_in, const int* in_sizes, int n_in,
                              void* d_out, int out_size, void* d_ws, size_t ws_size,
                              hipStream_t stream) {
  const float* xs   = (const float*)d_in[0];
  const int*   pid  = (const int*)d_in[1];
  const float* Waff = (const float*)d_in[2];
  const float* baff = (const float*)d_in[3];
  const float* Wqkv = (const float*)d_in[4];
  const float* bqkv = (const float*)d_in[5];
  const float* invf = (const float*)d_in[6];
  float* out = (float*)d_out;

  // workspace layout (~538 MB total)
  char* p = (char*)d_ws;
  bf16* A_hi  = (bf16*)p; p += (long)33554432 * 2;
  bf16* A_lo  = (bf16*)p; p += (long)33554432 * 2;
  bf16* Wa_hi = (bf16*)p; p += (long)16777216 * 2;
  bf16* Wa_lo = (bf16*)p; p += (long)16777216 * 2;
  bf16* Wq_hi = (bf16*)p; p += (long)50331648 * 2;
  bf16* Wq_lo = (bf16*)p; p += (long)50331648 * 2;
  bf16* h_hi  = (bf16*)p; p += (long)33554432 * 2;
  bf16* h_lo  = (bf16*)p; p += (long)33554432 * 2;
  float* cost = (float*)p; p += 65536 * 4;
  float* sint = (float*)p; p += 65536 * 4;

  split_kernel<<<2048, 256, 0, stream>>>(xs, A_hi, A_lo, 33554432 / 4);
  split_kernel<<<2048, 256, 0, stream>>>(Waff, Wa_hi, Wa_lo, 16777216 / 4);
  split_kernel<<<2048, 256, 0, stream>>>(Wqkv, Wq_hi, Wq_lo, 50331648 / 4);
  rope_table_kernel<<<256, 256, 0, stream>>>(invf, cost, sint);

  // GEMM1: 64 row-tiles x 32 col-tiles = 2048 blocks (4 bands)
  gemm_split_kernel<0><<<2048, 256, 0, stream>>>(A_hi, A_lo, Wa_hi, Wa_lo, baff,
                                                 h_hi, h_lo, nullptr, nullptr,
                                                 nullptr, nullptr);
  // GEMM2: 64 row-tiles x 96 col-tiles = 6144 blocks (12 bands)
  gemm_split_kernel<1><<<6144, 256, 0, stream>>>(h_hi, h_lo, Wq_hi, Wq_lo, bqkv,
                                                 nullptr, nullptr, out, pid, cost,
                                                 sint);
}